// Round 10
// baseline (287.934 us; speedup 1.0000x reference)
//
#include <hip/hip_runtime.h>

// Problem constants (GNNNet_678604833376): B=2, N=50000, D=128, E=640000
#define NNODES 50000
#define NBATCH 2
#define DIM    128
#define NEDGE  640000
#define M_TOT  (NBATCH*NNODES)   // 100000 rows for the GEMM
#define NXCD   8
#define NBL_N  196               // ceil(NNODES/256)
#define NTILE  391               // ceil(M_TOT/256)
#define NBL_E  2500              // ceil(NEDGE/256)

typedef unsigned short u16;
typedef unsigned int   u32;
typedef unsigned long long u64;

typedef __attribute__((ext_vector_type(8))) short bf16x8;   // 8 bf16 = 4 VGPRs
typedef __attribute__((ext_vector_type(4))) float f32x4;

__device__ __forceinline__ float bf2f(u16 u){ return __uint_as_float(((u32)u)<<16); }
__device__ __forceinline__ u16 f2bf(float f){
    u32 x = __float_as_uint(f);
    x += 0x7fffu + ((x>>16)&1u);   // round-to-nearest-even
    return (u16)(x>>16);
}

// ---------- transpose W (fp32) -> Wt (bf16); also zero part[] ----------
__global__ __launch_bounds__(256) void transposeW(const float* __restrict__ W1, u16* __restrict__ Wt1,
                                                  const float* __restrict__ W2, u16* __restrict__ Wt2,
                                                  u64* __restrict__ part){
    int i = blockIdx.x*256 + threadIdx.x;         // 128 x 256 = 32768 threads
    const float* W = (i < 16384) ? W1 : W2;
    u16* Wt       = (i < 16384) ? Wt1 : Wt2;
    int ii = i & 16383;
    int k = ii >> 7, n = ii & 127;
    Wt[n*DIM + k] = f2bf(W[ii]);
    for (int z = i; z < NXCD*NNODES; z += 32768) part[z] = 0;
}

// ---------- GEMM body: H = A @ W, swapped MFMA operands ----------
// A-op = Wt rows (m = feature), B-op = data rows (n = data-row).
// D[m=quad*4+reg][n=r] -> lane owns 4 consecutive features of one row ->
// epilogue = 32x 8B stores per lane (vs 128x 2B scatter).
__device__ __forceinline__ bf16x8 load_frag(const float* A, size_t off){
    const float4* ap = (const float4*)(A + off);
    float4 lo = ap[0], hi = ap[1];
    bf16x8 r;
    r[0] = (short)f2bf(lo.x); r[1] = (short)f2bf(lo.y);
    r[2] = (short)f2bf(lo.z); r[3] = (short)f2bf(lo.w);
    r[4] = (short)f2bf(hi.x); r[5] = (short)f2bf(hi.y);
    r[6] = (short)f2bf(hi.z); r[7] = (short)f2bf(hi.w);
    return r;
}
__device__ __forceinline__ bf16x8 load_frag(const u16* A, size_t off){
    return *(const bf16x8*)(A + off);
}

template <typename AT, bool PERM>
__device__ __forceinline__ void gemm_body(const AT* __restrict__ A,
                                          const u16* __restrict__ Wt,
                                          u16* __restrict__ H, int M, int bid){
    __shared__ u16 Wl[128][136];   // 272B row stride: 16B-aligned, breaks pow2
    int tid = threadIdx.x;
    {
        const uint4* src = (const uint4*)Wt;   // 2048 x 16B
        #pragma unroll
        for (int j = 0; j < 8; ++j){
            int g = tid + j*256;
            int n = g >> 4;
            int k = (g & 15) * 8;
            *(uint4*)&Wl[n][k] = src[g];
        }
    }
    __syncthreads();

    int wave = tid >> 6, lane = tid & 63;
    int quad = lane >> 4, r = lane & 15;
    int row0 = bid*256 + wave*64;

    f32x4 acc[4][8];               // [rowtile][featuretile]
    #pragma unroll
    for (int rt = 0; rt < 4; ++rt)
        #pragma unroll
        for (int mt = 0; mt < 8; ++mt)
            acc[rt][mt] = (f32x4){0.f,0.f,0.f,0.f};

    #pragma unroll
    for (int ks = 0; ks < 4; ++ks){
        bf16x8 bfr[4];             // data fragments (B-operand)
        #pragma unroll
        for (int rt = 0; rt < 4; ++rt){
            int row = row0 + rt*16 + r;
            if (row < M)
                bfr[rt] = load_frag(A, (size_t)row*DIM + ks*32 + quad*8);
            else
                bfr[rt] = (bf16x8){0,0,0,0,0,0,0,0};
        }
        #pragma unroll
        for (int mt = 0; mt < 8; ++mt){
            bf16x8 af = *(const bf16x8*)&Wl[mt*16 + r][ks*32 + quad*8];  // A-op = Wt
            #pragma unroll
            for (int rt = 0; rt < 4; ++rt)
                acc[rt][mt] = __builtin_amdgcn_mfma_f32_16x16x32_bf16(af, bfr[rt], acc[rt][mt], 0, 0, 0);
        }
    }

    // store: lane (quad,r) holds features mt*16+quad*4+{0..3} of row row0+rt*16+r
    #pragma unroll
    for (int rt = 0; rt < 4; ++rt){
        int row = row0 + rt*16 + r;
        if (row < M){
            size_t hrow;
            if (PERM){
                int b = (row >= NNODES);
                int n = row - (b ? NNODES : 0);
                hrow = (size_t)(2*n + b);       // batch-interleaved
            } else {
                hrow = (size_t)row;
            }
            u16* Hrow = H + hrow*DIM + quad*4;
            #pragma unroll
            for (int mt = 0; mt < 8; ++mt){
                uint2 pk;
                pk.x = (u32)f2bf(acc[rt][mt][0]) | ((u32)f2bf(acc[rt][mt][1]) << 16);
                pk.y = (u32)f2bf(acc[rt][mt][2]) | ((u32)f2bf(acc[rt][mt][3]) << 16);
                *(uint2*)(Hrow + mt*16) = pk;
            }
        }
    }
}

// ---------- count body: per-XCD partial histograms, L2-resident atomics ----------
__device__ __forceinline__ void count_body(const int* __restrict__ ei,
                                           const float* __restrict__ ea,
                                           u64* __restrict__ part,
                                           u32* __restrict__ rankpack, int bid){
    u32 xcc = __builtin_amdgcn_s_getreg(6164) & 7u;   // HW_REG_XCC_ID
    int e = bid*256 + threadIdx.x;
    if (e < NEDGE){
        int c = ei[NEDGE + e];
        u64 inc = (((u64)__float2uint_rn(ea[e] * 16777216.0f)) << 32) | 1ull;
        u64 old = __hip_atomic_fetch_add(&part[(size_t)xcc*NNODES + c], inc,
                                         __ATOMIC_RELAXED, __HIP_MEMORY_SCOPE_WORKGROUP);
        rankpack[e] = ((u32)old & 0xffffu) | (xcc << 16);
    }
}

// ---------- merged: gemm1 (blocks [0,NTILE)) + count (blocks [NTILE,NTILE+NBL_E)) ----------
__global__ __launch_bounds__(256) void gemm1_count_k(const float* __restrict__ x,
                                                     const u16* __restrict__ Wt1,
                                                     u16* __restrict__ h,
                                                     const int* __restrict__ ei,
                                                     const float* __restrict__ ea,
                                                     u64* __restrict__ part,
                                                     u32* __restrict__ rankpack){
    if (blockIdx.x < NTILE)
        gemm_body<float, true>(x, Wt1, h, M_TOT, blockIdx.x);
    else
        count_body(ei, ea, part, rankpack, blockIdx.x - NTILE);
}

__global__ __launch_bounds__(256) void gemm2_k(const u16* __restrict__ o1,
                                               const u16* __restrict__ Wt2,
                                               u16* __restrict__ h){
    gemm_body<u16, false>(o1, Wt2, h, M_TOT, blockIdx.x);
}

// ---------- fused reduce + block-scan ----------
__global__ __launch_bounds__(256) void scan1(const u64* __restrict__ part,
                                             int* __restrict__ cnt,
                                             int* __restrict__ poff,
                                             float* __restrict__ dinv,
                                             int* colstart, int* bsum){
    __shared__ int s[256];
    int tid = threadIdx.x;
    int n = blockIdx.x*256 + tid;
    int v = 0;
    if (n < NNODES){
        int run = 0; u64 fsum = 0;
        #pragma unroll
        for (int p = 0; p < NXCD; ++p){
            u64 pv = part[(size_t)p*NNODES + n];
            poff[p*NNODES + n] = run;
            run  += (int)(pv & 0xffffffffu);
            fsum += (pv >> 32);
        }
        cnt[n] = run;
        v = run;
        float deg = 1.0f + (float)fsum * (1.0f/16777216.0f);   // deg >= 1
        dinv[n] = rsqrtf(deg);
    }
    s[tid] = v; __syncthreads();
    #pragma unroll
    for (int off = 1; off < 256; off <<= 1){
        int t = (tid >= off) ? s[tid-off] : 0;
        __syncthreads();
        s[tid] += t;
        __syncthreads();
    }
    if (n < NNODES) colstart[n] = s[tid] - v;     // exclusive within block
    if (tid == 255) bsum[blockIdx.x] = s[255];
}

// ---------- CSR bucket fill + inline bsum-scan ----------
// epk[pos] = row | (bf16(norm) << 16)   (row < 50000 fits in 16 bits)
__global__ __launch_bounds__(256) void fill_k(const int* __restrict__ ei,
                                              const float* __restrict__ ea,
                                              const float* __restrict__ dinv,
                                              const int* __restrict__ colstart,
                                              const int* __restrict__ bsum,
                                              const int* __restrict__ poff,
                                              const u32* __restrict__ rankpack,
                                              int* __restrict__ colstartF,
                                              u32* __restrict__ epk){
    __shared__ int s[256];
    __shared__ int pre[256];
    int tid = threadIdx.x;
    int v = (tid < NBL_N) ? bsum[tid] : 0;
    s[tid] = v; __syncthreads();
    #pragma unroll
    for (int off = 1; off < 256; off <<= 1){
        int t = (tid >= off) ? s[tid-off] : 0;
        __syncthreads();
        s[tid] += t;
        __syncthreads();
    }
    pre[tid] = s[tid] - v;                        // exclusive prefix of bsum
    __syncthreads();

    int e = blockIdx.x*256 + tid;
    if (e < NEDGE){
        int r = ei[e], c = ei[NEDGE + e];
        u32 rp = rankpack[e];
        int base = colstart[c] + pre[c >> 8];     // final colstart for c
        colstartF[c] = base;
        int pos = base + poff[(rp >> 16)*NNODES + c] + (int)(rp & 0xffffu);
        float w = dinv[r] * ea[e] * dinv[c];
        epk[pos] = (u32)r | ((u32)f2bf(w) << 16);
    }
}

// ---------- gather-aggregate: one wave = one node, BOTH batches (R9) ----------
template <bool OUT_F32>
__global__ __launch_bounds__(256) void gather6_k(const u16* __restrict__ Hi,
                                                 const u32* __restrict__ epk,
                                                 const int* __restrict__ colstartF,
                                                 const int* __restrict__ cnt,
                                                 const float* __restrict__ dinv,
                                                 const float* __restrict__ bias,
                                                 void* __restrict__ out){
    int wave = threadIdx.x >> 6, lane = threadIdx.x & 63;
    int n = blockIdx.x*4 + wave;
    if (n >= NNODES) return;
    const char* Hb = (const char*)Hi;             // row stride 512 B (both batches)

    float a0, a1, a2, a3;
    {
        uint2 sv = *(const uint2*)(Hb + (size_t)n*512 + lane*8);
        float dn = dinv[n], dn2 = dn*dn;
        a0 = dn2*__uint_as_float(sv.x << 16);
        a1 = dn2*__uint_as_float(sv.x & 0xffff0000u);
        a2 = dn2*__uint_as_float(sv.y << 16);
        a3 = dn2*__uint_as_float(sv.y & 0xffff0000u);
    }

    int s = colstartF[n], c = cnt[n];
    for (int base = 0; base < c; base += 64){
        int m = min(64, c - base);
        u32 em = 0;                               // pad: row 0, weight +0.0f
        if (lane < m) em = epk[s + base + lane];
        for (int j = 0; j < m; j += 8){           // 8 edges per iter in flight
            #pragma unroll
            for (int g = 0; g < 8; ++g){
                u32 me = __shfl(em, j + g);       // max idx 56+7 = 63
                uint2 v = *(const uint2*)(Hb + (size_t)(me & 0xffffu)*512 + lane*8);
                float w = __uint_as_float(me & 0xffff0000u);
                a0 = fmaf(w, __uint_as_float(v.x << 16), a0);
                a1 = fmaf(w, __uint_as_float(v.x & 0xffff0000u), a1);
                a2 = fmaf(w, __uint_as_float(v.y << 16), a2);
                a3 = fmaf(w, __uint_as_float(v.y & 0xffff0000u), a3);
            }
        }
    }

    int sub = lane & 31, b = lane >> 5;
    float4 bb = ((const float4*)bias)[sub];       // cols [4*sub .. 4*sub+4)
    a0 = fmaxf(a0 + bb.x, 0.f);
    a1 = fmaxf(a1 + bb.y, 0.f);
    a2 = fmaxf(a2 + bb.z, 0.f);
    a3 = fmaxf(a3 + bb.w, 0.f);
    if (OUT_F32){
        float* O = (float*)out + ((size_t)b*NNODES + n)*DIM + sub*4;
        *(float4*)O = make_float4(a0, a1, a2, a3);
    } else {
        char* O = (char*)out + (size_t)n*512 + lane*8;
        uint2 pk;
        pk.x = (u32)f2bf(a0) | ((u32)f2bf(a1) << 16);
        pk.y = (u32)f2bf(a2) | ((u32)f2bf(a3) << 16);
        *(uint2*)O = pk;
    }
}

// ---------- launch ----------
extern "C" void kernel_launch(void* const* d_in, const int* in_sizes, int n_in,
                              void* d_out, int out_size, void* d_ws, size_t ws_size,
                              hipStream_t stream){
    const float* x  = (const float*)d_in[0];
    const int*   ei = (const int*)  d_in[1];
    const float* ea = (const float*)d_in[2];
    const float* W1 = (const float*)d_in[3];
    const float* b1 = (const float*)d_in[4];
    const float* W2 = (const float*)d_in[5];
    const float* b2 = (const float*)d_in[6];

    char* p = (char*)d_ws;
    auto alloc = [&](size_t bytes)->char*{ char* r = p; p += (bytes + 511) & ~(size_t)511; return r; };
    u64*   part     = (u64*)  alloc((size_t)NXCD*NNODES*8);   // 3.2 MB partial histograms
    u32*   rankpack = (u32*)  alloc((size_t)NEDGE*4);
    int*   poff     = (int*)  alloc((size_t)NXCD*NNODES*4);
    float* dinv     = (float*)alloc(NNODES*4);
    int*   cnt      = (int*)  alloc(NNODES*4);
    int*   colstart = (int*)  alloc(NNODES*4);
    int*   colstartF= (int*)  alloc(NNODES*4);
    int*   bsum     = (int*)  alloc(1024);
    u32*   epk      = (u32*)  alloc((size_t)NEDGE*4);
    u16*   Wt1      = (u16*)  alloc(DIM*DIM*2);
    u16*   Wt2      = (u16*)  alloc(DIM*DIM*2);
    u16*   h        = (u16*)  alloc((size_t)M_TOT*DIM*2);   // bf16, batch-interleaved
    u16*   o1       = (u16*)  alloc((size_t)M_TOT*DIM*2);   // bf16, batch-interleaved

    const int NBL_G = (NNODES + 3)/4;       // 12500 (4 node-waves per block)

    transposeW<<<128, 256, 0, stream>>>(W1, Wt1, W2, Wt2, part);
    gemm1_count_k<<<NTILE + NBL_E, 256, 0, stream>>>(x, Wt1, h, ei, ea, part, rankpack);
    scan1 <<<NBL_N, 256, 0, stream>>>(part, cnt, poff, dinv, colstart, bsum);
    fill_k<<<NBL_E, 256, 0, stream>>>(ei, ea, dinv, colstart, bsum, poff, rankpack, colstartF, epk);

    gather6_k<false><<<NBL_G, 256, 0, stream>>>(h, epk, colstartF, cnt, dinv, b1, o1);
    gemm2_k<<<NTILE, 256, 0, stream>>>(o1, Wt2, h);
    gather6_k<true ><<<NBL_G, 256, 0, stream>>>(h, epk, colstartF, cnt, dinv, b2, d_out);
}